// Round 3
// baseline (785.043 us; speedup 1.0000x reference)
//
#include <hip/hip_runtime.h>
#include <math.h>

#define NTOK 16384
#define HDIM 2048
#define KNOI 25
#define RPW  4            // rows per wave (ds_read amortization: 1 read -> 16 FMAs)
#define WPB  4            // waves per block (256 threads) -> 16 rows/block
#define CHUNK 256         // floats of H per chunk
#define NCHUNK (HDIM / CHUNK)   // 8

typedef __attribute__((address_space(3))) unsigned lds_uint;
typedef __attribute__((address_space(1))) const unsigned glob_uint;

// Async global->LDS, 16B per lane, dest = uniform base + lane*16 (HW rule).
__device__ __forceinline__ void stage16(const void* g, void* l) {
    __builtin_amdgcn_global_load_lds((glob_uint*)g, (lds_uint*)l, 16, 0, 0);
}

// RPW=4: each ds_read_b128 of a noise chunk feeds 4 token rows, halving the
// LDS-pipe load vs RPW=2 (per-CU: ~16us ds_read vs 43us HBM -> HBM-bound).
// VGPR need ~150 (104 acc + 32 prefetch + addressing): waves_per_eu(3,3)
// sets the 170-reg / 3-waves-per-EU point explicitly. Round 1 proved that
// letting the allocator chase occupancy (84 regs) spills the accumulators
// (2 GB scratch traffic, 18x); round 2's (4,4)/128 cap would spill ~25 regs.
__global__ __launch_bounds__(256)
__attribute__((amdgpu_waves_per_eu(3, 3)))
void nce_main(
    const float* __restrict__ input,
    const float* __restrict__ weight,
    const float* __restrict__ bias,
    const float* __restrict__ uni,
    const int* __restrict__ target,
    const int* __restrict__ noise,
    float* __restrict__ out)
{
    __shared__ float4 ldsn[KNOI * (CHUNK / 4)];   // 25 rows x 1KB = 25.6 KB

    float* pmt = out;
    float* pnt = out + NTOK;
    float* pmn = out + 2 * NTOK;
    float* pnn = out + 2 * NTOK + NTOK * KNOI;

    const int lane = threadIdx.x & 63;
    const int wave = threadIdx.x >> 6;
    int row0 = (blockIdx.x * WPB + wave) * RPW;
    row0 = __builtin_amdgcn_readfirstlane(row0);   // wave-uniform -> SGPR

    // Noise byte offsets only (uniform -> SGPRs).
    unsigned noffb[KNOI];
#pragma unroll
    for (int k = 0; k < KNOI; ++k)
        noffb[k] = (unsigned)noise[k] * (unsigned)(HDIM * 4);

    unsigned toffb[RPW], ioffb[RPW];
#pragma unroll
    for (int r = 0; r < RPW; ++r) {
        toffb[r] = (unsigned)target[row0 + r] * (unsigned)(HDIM * 4);
        ioffb[r] = (unsigned)(row0 + r) * (unsigned)(HDIM * 4);
    }

    const char* wb = (const char*)weight;
    const char* ib = (const char*)input;
    const unsigned laneoff = (unsigned)lane * 16u;

    float acc[RPW][KNOI];
    float acct[RPW];
#pragma unroll
    for (int r = 0; r < RPW; ++r) {
        acct[r] = 0.f;
#pragma unroll
        for (int k = 0; k < KNOI; ++k) acc[r][k] = 0.f;
    }

    // Prefetch chunk 0's input/target float4s.
    float4 inv[RPW], tgv[RPW];
#pragma unroll
    for (int r = 0; r < RPW; ++r) {
        inv[r] = *(const float4*)(ib + ioffb[r] + laneoff);
        tgv[r] = *(const float4*)(wb + toffb[r] + laneoff);
    }

    for (int c = 0; c < NCHUNK; ++c) {
        const unsigned cb = (unsigned)c * (unsigned)(CHUNK * 4);

        // Stage noise chunk: wave w loads rows k = j*4+w (wave-uniform branch).
#pragma unroll
        for (int j = 0; j < 7; ++j) {
            const int k = j * WPB + wave;
            if (k < KNOI)
                stage16(wb + noffb[k] + cb + laneoff, &ldsn[k * (CHUNK / 4)]);
        }
        __syncthreads();   // drains staging (vmcnt) + makes LDS visible

        // Snapshot current chunk's in/target, then prefetch next chunk's.
        float4 in[RPW], tg[RPW];
#pragma unroll
        for (int r = 0; r < RPW; ++r) { in[r] = inv[r]; tg[r] = tgv[r]; }
        const unsigned nb = (unsigned)((c + 1) & (NCHUNK - 1)) * (unsigned)(CHUNK * 4);
#pragma unroll
        for (int r = 0; r < RPW; ++r) {
            inv[r] = *(const float4*)(ib + ioffb[r] + nb + laneoff);
            tgv[r] = *(const float4*)(wb + toffb[r] + nb + laneoff);
        }

#pragma unroll
        for (int k = 0; k < KNOI; ++k) {
            const float4 w = ldsn[k * (CHUNK / 4) + lane];   // ds_read_b128
#pragma unroll
            for (int r = 0; r < RPW; ++r)
                acc[r][k] += in[r].x * w.x + in[r].y * w.y
                           + in[r].z * w.z + in[r].w * w.w;
        }
#pragma unroll
        for (int r = 0; r < RPW; ++r)
            acct[r] += in[r].x * tg[r].x + in[r].y * tg[r].y
                     + in[r].z * tg[r].z + in[r].w * tg[r].w;

        __syncthreads();   // protect LDS before next chunk's staging
    }

    // Pack-halving multi-value wave reduction (verified rounds 1-2): 32 slots
    // (25 noise + target + 6 zero pads), 5 pairing steps + 1 final butterfly
    // = 31 shuffles/row vs 156 per-value. Lane L ends holding value
    // m = bits(L5..L1); even lane of each pair stores -> parallel epilogue.
    const int m = ((lane >> 5) & 1) | (((lane >> 4) & 1) << 1)
                | (((lane >> 3) & 1) << 2) | (((lane >> 2) & 1) << 3)
                | (((lane >> 1) & 1) << 4);

#pragma unroll
    for (int r = 0; r < RPW; ++r) {
        float v[32];   // fully unrolled -> stays in registers
#pragma unroll
        for (int k = 0; k < KNOI; ++k) v[k] = acc[r][k];
        v[KNOI] = acct[r];
#pragma unroll
        for (int j = KNOI + 1; j < 32; ++j) v[j] = 0.f;

#pragma unroll
        for (int s = 0; s < 5; ++s) {
            const int h  = 32 >> s;   // lane bit / shfl mask: 32,16,8,4,2
            const int np = 16 >> s;   // pairs this step
#pragma unroll
            for (int i = 0; i < np; ++i) {
                const float lo = v[2 * i], hi = v[2 * i + 1];
                const bool up = (lane & h) != 0;
                const float send = up ? lo : hi;
                const float recv = __shfl_xor(send, h, 64);
                v[i] = (up ? hi : lo) + recv;
            }
        }
        const float tot = v[0] + __shfl_xor(v[0], 1, 64);

        if ((lane & 1) == 0) {
            const int row = row0 + r;
            if (m < KNOI) {
                const int nk = noise[m];                     // L2-hot gathers
                pmn[row * KNOI + m] = expf(tot + bias[nk]);
                pnn[row * KNOI + m] = uni[nk];
            } else if (m == KNOI) {
                const int tk = (int)(toffb[r] >> 13);        // off = idx*8192
                pmt[row] = expf(tot + bias[tk]);
                pnt[row] = uni[tk];
            }
        }
    }
}

extern "C" void kernel_launch(void* const* d_in, const int* in_sizes, int n_in,
                              void* d_out, int out_size, void* d_ws, size_t ws_size,
                              hipStream_t stream) {
    const float* input  = (const float*)d_in[0];
    const float* weight = (const float*)d_in[1];
    const float* bias   = (const float*)d_in[2];
    const float* uni    = (const float*)d_in[3];
    const int*   target = (const int*)d_in[4];
    const int*   noise  = (const int*)d_in[5];
    float* out = (float*)d_out;

    const dim3 grid(NTOK / (WPB * RPW));   // 1024 blocks x 16 rows
    const dim3 block(256);
    hipLaunchKernelGGL(nce_main, grid, block, 0, stream,
                       input, weight, bias, uni, target, noise, out);
}